// Round 3
// baseline (458.741 us; speedup 1.0000x reference)
//
#include <hip/hip_runtime.h>

// Problem dims
#define S_ 32
#define T_ 64
#define B_ 64
#define V_ 32000
#define E_ 128
#define H_ 128
#define G_ 128
#define C_ 5

typedef short s8v __attribute__((ext_vector_type(8)));   // 8 bf16 payload
typedef __bf16 b8v __attribute__((ext_vector_type(8)));
typedef float f32x4 __attribute__((ext_vector_type(4)));

// --- MFMA wrapper: tolerate either builtin operand signature (short8 or bf16x8)
template <typename V>
__device__ inline auto mfma_sel(V a, V b, f32x4 c, int)
    -> decltype(__builtin_amdgcn_mfma_f32_16x16x32_bf16(a, b, c, 0, 0, 0)) {
  return __builtin_amdgcn_mfma_f32_16x16x32_bf16(a, b, c, 0, 0, 0);
}
template <typename V>
__device__ inline f32x4 mfma_sel(V a, V b, f32x4 c, long) {
  return __builtin_amdgcn_mfma_f32_16x16x32_bf16(
      __builtin_bit_cast(b8v, a), __builtin_bit_cast(b8v, b), c, 0, 0, 0);
}
__device__ inline f32x4 mfma16(s8v a, s8v b, f32x4 c) { return mfma_sel(a, b, c, 0); }

__device__ inline float b2f(unsigned short u) {
  union { unsigned int i; float f; } v; v.i = ((unsigned int)u) << 16; return v.f;
}
__device__ inline unsigned short f2b(float f) {
  union { float f; unsigned int i; } v; v.f = f;
  unsigned int r = (v.i + 0x7fffu + ((v.i >> 16) & 1u)) >> 16;
  return (unsigned short)r;
}
__device__ inline s8v cvt8(const float* p) {
  const float4 a = *(const float4*)p;
  const float4 b = *(const float4*)(p + 4);
  s8v r;
  r[0] = (short)f2b(a.x); r[1] = (short)f2b(a.y);
  r[2] = (short)f2b(a.z); r[3] = (short)f2b(a.w);
  r[4] = (short)f2b(b.x); r[5] = (short)f2b(b.y);
  r[6] = (short)f2b(b.z); r[7] = (short)f2b(b.w);
  return r;
}
__device__ inline float sigm(float x) {
  x = fminf(fmaxf(x, -30.f), 30.f);
  return 1.f / (1.f + __expf(-x));
}
__device__ inline float tanh_f(float x) {
  x = fminf(fmaxf(x, -15.f), 15.f);
  float e = __expf(2.f * x);
  return (e - 1.f) / (e + 1.f);
}

// LDS-only barrier: waits LDS ops, does NOT drain vmcnt — global loads issued
// before this stay in flight across it (cross-wave data here is LDS-only).
__device__ inline void lds_barrier() {
  asm volatile("s_waitcnt lgkmcnt(0)\n\ts_barrier" ::: "memory");
}

// ============================================================================
// K1: gtab[v][c] = sum_e emb[v][e]*Wih_intra[c][e] + bih[c]. MFMA GEMM.
// Blocks 3000..3003: coalesced LDS-tiled transpose of W_W_intra -> wta bf16.
// ============================================================================
__global__ __launch_bounds__(256) void k_gtab(
    const float* __restrict__ emb,
    const float* __restrict__ wih,   // [768][128] fp32
    const float* __restrict__ bih,   // [768] fp32
    const float* __restrict__ wwi,   // [256][256] fp32 (h-major)
    unsigned short* __restrict__ gtab,   // [V][768] bf16
    unsigned short* __restrict__ wta)    // [256][256] bf16 (n-major)
{
  __shared__ __align__(16) unsigned short smem[64 * 264];  // union: alds / tbuf
  const int bid = blockIdx.x, tid = threadIdx.x;
  if (bid >= 3000) {  // LDS-tiled transpose, 4 blocks x 64 n-rows
    const int n0 = (bid - 3000) * 64;
    for (int i = 0; i < 64; ++i) {
      int cid = i * 256 + tid;
      int k = cid >> 6, nl = cid & 63;
      smem[nl * 264 + k] = f2b(wwi[k * 256 + n0 + nl]);  // coalesced read
    }
    __syncthreads();
    for (int i = 0; i < 8; ++i) {
      int cid = i * 256 + tid;
      int nl = cid >> 5, k8 = cid & 31;
      *(int4*)&wta[(size_t)(n0 + nl) * 256 + k8 * 8] =
          *(const int4*)&smem[nl * 264 + k8 * 8];        // coalesced write
    }
    return;
  }
  const int mchunk = bid / 6, nchunk = bid % 6;
  const int vbase = mchunk * 64, nbase = nchunk * 128;
  for (int i = 0; i < 8; ++i) {
    int cid = i * 256 + tid;           // 2048 chunks of 4 floats
    int row = cid >> 5, kc = cid & 31;
    float4 v = *(const float4*)&emb[(size_t)(vbase + row) * 128 + kc * 4];
    ushort4 u; u.x = f2b(v.x); u.y = f2b(v.y); u.z = f2b(v.z); u.w = f2b(v.w);
    *(ushort4*)&smem[row * 136 + kc * 4] = u;
  }
  __syncthreads();
  const int w = tid >> 6, l = tid & 63, q = l >> 4, ln = l & 15;
  s8v bf[2][4];
  float bias[2];
  for (int nt = 0; nt < 2; ++nt) {
    int c = nbase + (w * 2 + nt) * 16 + ln;
    bias[nt] = bih[c];
    for (int kf = 0; kf < 4; ++kf)
      bf[nt][kf] = cvt8(&wih[(size_t)c * 128 + kf * 32 + q * 8]);
  }
  for (int mt = 0; mt < 4; ++mt) {
    s8v af[4];
    for (int kf = 0; kf < 4; ++kf)
      af[kf] = *(const s8v*)&smem[(mt * 16 + ln) * 136 + kf * 32 + q * 8];
    for (int nt = 0; nt < 2; ++nt) {
      f32x4 acc = {0.f, 0.f, 0.f, 0.f};
      for (int kf = 0; kf < 4; ++kf) acc = mfma16(af[kf], bf[nt][kf], acc);
      const int col = nbase + (w * 2 + nt) * 16 + ln;
      for (int r = 0; r < 4; ++r) {
        const int row = vbase + mt * 16 + q * 4 + r;
        gtab[(size_t)row * 768 + col] = f2b(acc[r] + bias[nt]);
      }
    }
  }
}

// ============================================================================
// K2: intra biGRU. Grid 512 = (s, dir, b-octet of 8) -> 2 blocks/CU.
// N=16 MFMA tile holds 8 real batches (cols 8..15 duplicate 0..7).
// Double-buffered h in LDS, ONE lds-only barrier/step, gather prefetched
// one step ahead (stays in flight across the barrier).
// ============================================================================
__global__ __launch_bounds__(512, 4) void k_intra(
    const int* __restrict__ tokens,
    const unsigned short* __restrict__ gtab,  // bf16 internal
    const float* __restrict__ whh,            // [2][384][128] fp32
    const float* __restrict__ bhh,            // [2][384] fp32
    unsigned short* __restrict__ iout)        // [S*T*B][256] bf16 internal
{
  const int bid = blockIdx.x;
  const int s = bid >> 4, dir = (bid >> 3) & 1, bq = bid & 7;
  const int bbase = bq * 8;
  const int tid = threadIdx.x;
  const int w = tid >> 6, l = tid & 63, q = l >> 4, ln = l & 15;
  const int tln = ln & 7;
  const int gbase = w * 16, g0 = gbase + q * 4;

  __shared__ __align__(16) unsigned short hb[2][16 * 136];
  __shared__ int tokl[T_ * 8];

  for (int i = tid; i < 2 * 16 * 136; i += 512) ((unsigned short*)hb)[i] = 0;
  for (int i = tid; i < T_ * 8; i += 512) {
    int t = i >> 3, bl = i & 7;
    tokl[i] = tokens[(s * T_ + t) * B_ + bbase + bl];
  }

  s8v af[3][4];
  float hbias[3][4];
  const float* whd = whh + (size_t)dir * (384 * 128);
  const float* bhd = bhh + dir * 384;
  for (int g3 = 0; g3 < 3; ++g3) {
    const int R = g3 * 128 + gbase;
    for (int kf = 0; kf < 4; ++kf)
      af[g3][kf] = cvt8(&whd[(size_t)(R + ln) * 128 + kf * 32 + q * 8]);
    for (int r = 0; r < 4; ++r)
      hbias[g3][r] = bhd[R + q * 4 + r];
  }
  float h[4] = {0.f, 0.f, 0.f, 0.f};
  const int b = bbase + tln;
  __syncthreads();

  // prefetch step 0's gate inputs
  {
    const int t0 = dir ? (T_ - 1) : 0;
    const unsigned short* gr = gtab + (size_t)tokl[t0 * 8 + tln] * 768 + dir * 384 + g0;
    // fallthrough into loop-carried regs below
  }
  int t0 = dir ? (T_ - 1) : 0;
  const unsigned short* gr0 = gtab + (size_t)tokl[t0 * 8 + tln] * 768 + dir * 384 + g0;
  ushort4 xr = *(const ushort4*)&gr0[0];
  ushort4 xz = *(const ushort4*)&gr0[128];
  ushort4 xn = *(const ushort4*)&gr0[256];

  int p = 0;
  for (int step = 0; step < T_; ++step) {
    const int t = dir ? (T_ - 1 - step) : step;
    const int t1 = dir ? (t > 0 ? t - 1 : 0) : (t < T_ - 1 ? t + 1 : T_ - 1);
    // prefetch next step's gates (in flight across the barrier)
    const unsigned short* grn =
        gtab + (size_t)tokl[t1 * 8 + tln] * 768 + dir * 384 + g0;
    const ushort4 xrn = *(const ushort4*)&grn[0];
    const ushort4 xzn = *(const ushort4*)&grn[128];
    const ushort4 xnn = *(const ushort4*)&grn[256];

    s8v bfr[4];
    for (int kf = 0; kf < 4; ++kf)
      bfr[kf] = *(const s8v*)&hb[p][ln * 136 + kf * 32 + q * 8];
    f32x4 c0 = {0.f, 0.f, 0.f, 0.f}, c1 = c0, c2 = c0;
    for (int kf = 0; kf < 4; ++kf) {
      c0 = mfma16(af[0][kf], bfr[kf], c0);
      c1 = mfma16(af[1][kf], bfr[kf], c1);
      c2 = mfma16(af[2][kf], bfr[kf], c2);
    }

    const unsigned short* xrp = (const unsigned short*)&xr;
    const unsigned short* xzp = (const unsigned short*)&xz;
    const unsigned short* xnp = (const unsigned short*)&xn;
    unsigned short hnb[4];
    for (int r = 0; r < 4; ++r) {
      float rr = sigm(b2f(xrp[r]) + c0[r] + hbias[0][r]);
      float zz = sigm(b2f(xzp[r]) + c1[r] + hbias[1][r]);
      float nn = tanh_f(b2f(xnp[r]) + rr * (c2[r] + hbias[2][r]));
      float hv = (1.f - zz) * nn + zz * h[r];
      h[r] = hv;
      hnb[r] = f2b(hv);
    }
    ushort4 hv4; hv4.x = hnb[0]; hv4.y = hnb[1]; hv4.z = hnb[2]; hv4.w = hnb[3];
    *(ushort4*)&hb[p ^ 1][ln * 136 + g0] = hv4;
    if (ln < 8)
      *(ushort4*)&iout[((size_t)(s * T_ + t) * B_ + b) * 256 + dir * 128 + g0] = hv4;
    lds_barrier();
    p ^= 1;
    xr = xrn; xz = xzn; xn = xnn;
  }
}

// ============================================================================
// K3a: partial a1 logits = proj . tanh(iout @ W_W_intra + b), one N-half per
// launch, 256 rows/block (grid 512). Halves write independent arrays.
// ============================================================================
__global__ __launch_bounds__(256) void k_attn1(
    const unsigned short* __restrict__ iout,  // bf16 internal
    const unsigned short* __restrict__ wta,   // bf16 [256][256] n-major
    const float* __restrict__ bint,           // [256] fp32
    const float* __restrict__ proj,           // [256] fp32
    float* __restrict__ a1h, int half)
{
  __shared__ __align__(16) unsigned short wlds[128 * 256];  // 64 KB, XOR-swizzled
  const int tid = threadIdx.x, bid = blockIdx.x;
  const int nbg = half * 128;
  for (int i = 0; i < 16; ++i) {
    int cid = i * 256 + tid;          // 4096 16B chunks
    int n = cid >> 5, kc = cid & 31;
    *(int4*)&wlds[n * 256 + ((kc ^ (n & 15)) << 3)] =
        *(const int4*)&wta[(size_t)(nbg + n) * 256 + kc * 8];
  }
  __syncthreads();
  const int w = tid >> 6, l = tid & 63, q = l >> 4, ln = l & 15;
  const int rbase = bid * 256;
  for (int mt4 = 0; mt4 < 4; ++mt4) {
    const int mt = w * 4 + mt4;
    const int rowa = rbase + mt * 16 + ln;
    s8v af[8];
    for (int kf = 0; kf < 8; ++kf)
      af[kf] = *(const s8v*)&iout[(size_t)rowa * 256 + kf * 32 + q * 8];
    float p0 = 0.f, p1 = 0.f, p2 = 0.f, p3 = 0.f;
    for (int nt = 0; nt < 8; ++nt) {
      const int nloc = nt * 16 + ln;
      f32x4 c = {0.f, 0.f, 0.f, 0.f};
      for (int kf = 0; kf < 8; ++kf) {
        s8v bf = *(const s8v*)&wlds[nloc * 256 + (((kf * 4 + q) ^ (nloc & 15)) << 3)];
        c = mfma16(af[kf], bf, c);
      }
      const int ncol = nbg + nloc;
      const float bb = bint[ncol], pp = proj[ncol];
      p0 += pp * tanh_f(c[0] + bb);
      p1 += pp * tanh_f(c[1] + bb);
      p2 += pp * tanh_f(c[2] + bb);
      p3 += pp * tanh_f(c[3] + bb);
    }
    for (int d = 1; d < 16; d <<= 1) {
      p0 += __shfl_xor(p0, d);
      p1 += __shfl_xor(p1, d);
      p2 += __shfl_xor(p2, d);
      p3 += __shfl_xor(p3, d);
    }
    if (ln == 0) {
      const int row = rbase + mt * 16 + q * 4;
      a1h[row] = p0; a1h[row + 1] = p1; a1h[row + 2] = p2; a1h[row + 3] = p3;
    }
  }
}

// ============================================================================
// K3b: softmax over T per (s,b) + weighted sum -> sent_vecs fp32 [S*B][256]
// ============================================================================
__global__ __launch_bounds__(256) void k_attn2(
    const float* __restrict__ a1p, const float* __restrict__ a1q,
    const unsigned short* __restrict__ iout,
    float* __restrict__ sv)
{
  const int bid = blockIdx.x;
  const int s = bid >> 6, b = bid & 63;
  const int tid = threadIdx.x;
  __shared__ float wgt[T_];
  if (tid < 64) {
    const int idx = (s * T_ + tid) * B_ + b;
    float lg = a1p[idx] + a1q[idx];
    float m = lg;
    for (int d = 1; d < 64; d <<= 1) m = fmaxf(m, __shfl_xor(m, d));
    float e = __expf(lg - m);
    float sum = e;
    for (int d = 1; d < 64; d <<= 1) sum += __shfl_xor(sum, d);
    wgt[tid] = e / sum;
  }
  __syncthreads();
  float acc = 0.f;
  for (int t = 0; t < T_; ++t)
    acc += wgt[t] * b2f(iout[((size_t)(s * T_ + t) * B_ + b) * 256 + tid]);
  sv[(size_t)(s * B_ + b) * 256 + tid] = acc;
}

// ============================================================================
// K4: inter input gates xgi[dir][s*64+b][384] = sv @ Wih_inter^T + bih_inter
// ============================================================================
__global__ __launch_bounds__(256) void k_xgi(
    const float* __restrict__ sv,
    const float* __restrict__ wihI,  // [768][256] fp32
    const float* __restrict__ bihI,  // [768] fp32
    float* __restrict__ xgi)         // [2][2048][384]
{
  const int bid = blockIdx.x, tid = threadIdx.x;
  const int r0 = bid * 8;
  __shared__ float svl[8 * 256];
  for (int i = 0; i < 8; ++i) svl[i * 256 + tid] = sv[(size_t)(r0 + i) * 256 + tid];
  __syncthreads();
  for (int cc = 0; cc < 3; ++cc) {
    const int c = cc * 256 + tid;
    const float bias = bihI[c];
    float acc[8];
    for (int i = 0; i < 8; ++i) acc[i] = bias;
    const float* wr = wihI + (size_t)c * 256;
    for (int hh = 0; hh < 256; ++hh) {
      const float wv = wr[hh];
      for (int i = 0; i < 8; ++i) acc[i] += wv * svl[i * 256 + hh];
    }
    const int dir = c / 384, g = c % 384;
    for (int i = 0; i < 8; ++i)
      xgi[((size_t)dir * 2048 + r0 + i) * 384 + g] = acc[i];
  }
}

// ============================================================================
// K5: inter biGRU. Grid 16 = (dir, b-octet). Same pipelined structure as K2.
// ============================================================================
__global__ __launch_bounds__(512, 4) void k_inter(
    const float* __restrict__ xgi,
    const float* __restrict__ whh,   // [2][384][128] fp32
    const float* __restrict__ bhh,   // [2][384] fp32
    float* __restrict__ io2)         // [S*B][256] fp32
{
  const int bid = blockIdx.x;
  const int dir = bid >> 3, bq = bid & 7, bbase = bq * 8;
  const int tid = threadIdx.x;
  const int w = tid >> 6, l = tid & 63, q = l >> 4, ln = l & 15;
  const int tln = ln & 7;
  const int gbase = w * 16, g0 = gbase + q * 4;
  __shared__ __align__(16) unsigned short hb[2][16 * 136];
  for (int i = tid; i < 2 * 16 * 136; i += 512) ((unsigned short*)hb)[i] = 0;
  s8v af[3][4];
  float hbias[3][4];
  const float* whd = whh + (size_t)dir * (384 * 128);
  const float* bhd = bhh + dir * 384;
  for (int g3 = 0; g3 < 3; ++g3) {
    const int R = g3 * 128 + gbase;
    for (int kf = 0; kf < 4; ++kf)
      af[g3][kf] = cvt8(&whd[(size_t)(R + ln) * 128 + kf * 32 + q * 8]);
    for (int r = 0; r < 4; ++r)
      hbias[g3][r] = bhd[R + q * 4 + r];
  }
  float h[4] = {0.f, 0.f, 0.f, 0.f};
  const int b = bbase + tln;
  __syncthreads();

  const int s0 = dir ? (S_ - 1) : 0;
  const float* xp0 = xgi + ((size_t)dir * 2048 + s0 * 64 + b) * 384 + g0;
  float4 vr = *(const float4*)&xp0[0];
  float4 vz = *(const float4*)&xp0[128];
  float4 vn = *(const float4*)&xp0[256];

  int p = 0;
  for (int step = 0; step < S_; ++step) {
    const int sI = dir ? (S_ - 1 - step) : step;
    const int s1 = dir ? (sI > 0 ? sI - 1 : 0) : (sI < S_ - 1 ? sI + 1 : S_ - 1);
    const float* xpn = xgi + ((size_t)dir * 2048 + s1 * 64 + b) * 384 + g0;
    const float4 vrn = *(const float4*)&xpn[0];
    const float4 vzn = *(const float4*)&xpn[128];
    const float4 vnn = *(const float4*)&xpn[256];

    s8v bfr[4];
    for (int kf = 0; kf < 4; ++kf)
      bfr[kf] = *(const s8v*)&hb[p][ln * 136 + kf * 32 + q * 8];
    f32x4 c0 = {0.f, 0.f, 0.f, 0.f}, c1 = c0, c2 = c0;
    for (int kf = 0; kf < 4; ++kf) {
      c0 = mfma16(af[0][kf], bfr[kf], c0);
      c1 = mfma16(af[1][kf], bfr[kf], c1);
      c2 = mfma16(af[2][kf], bfr[kf], c2);
    }
    const float irv[4] = {vr.x, vr.y, vr.z, vr.w};
    const float izv[4] = {vz.x, vz.y, vz.z, vz.w};
    const float inv[4] = {vn.x, vn.y, vn.z, vn.w};
    unsigned short hnb[4];
    for (int r = 0; r < 4; ++r) {
      float rr = sigm(irv[r] + c0[r] + hbias[0][r]);
      float zz = sigm(izv[r] + c1[r] + hbias[1][r]);
      float nn = tanh_f(inv[r] + rr * (c2[r] + hbias[2][r]));
      float hv = (1.f - zz) * nn + zz * h[r];
      h[r] = hv;
      hnb[r] = f2b(hv);
    }
    ushort4 hv4; hv4.x = hnb[0]; hv4.y = hnb[1]; hv4.z = hnb[2]; hv4.w = hnb[3];
    *(ushort4*)&hb[p ^ 1][ln * 136 + g0] = hv4;
    if (ln < 8) {
      float4 of4; of4.x = h[0]; of4.y = h[1]; of4.z = h[2]; of4.w = h[3];
      *(float4*)&io2[((size_t)(sI * 64 + b)) * 256 + dir * 128 + g0] = of4;
    }
    lds_barrier();
    p ^= 1;
    vr = vrn; vz = vzn; vn = vnn;
  }
}

// ============================================================================
// K6: a2[s*64+b] = proj_inter . tanh(io2 @ W_W_inter + b_inter)  (no softmax)
// ============================================================================
__global__ __launch_bounds__(256) void k_attn_i(
    const float* __restrict__ io2,
    const float* __restrict__ wwI,   // [256][256] fp32 h-major
    const float* __restrict__ bI,
    const float* __restrict__ projI,
    float* __restrict__ a2)          // [2048]
{
  const int bid = blockIdx.x, tid = threadIdx.x;
  const int r0 = bid * 8;
  __shared__ float iol[8 * 256];
  __shared__ float red[4 * 8];
  for (int i = 0; i < 8; ++i) iol[i * 256 + tid] = io2[(size_t)(r0 + i) * 256 + tid];
  __syncthreads();
  float acc[8];
  for (int i = 0; i < 8; ++i) acc[i] = 0.f;
  for (int hh = 0; hh < 256; ++hh) {
    const float wv = wwI[hh * 256 + tid];
    for (int i = 0; i < 8; ++i) acc[i] += wv * iol[i * 256 + hh];
  }
  const float bb = bI[tid], pp = projI[tid];
  float p[8];
  for (int i = 0; i < 8; ++i) p[i] = pp * tanh_f(acc[i] + bb);
  for (int d = 1; d < 64; d <<= 1)
    for (int i = 0; i < 8; ++i) p[i] += __shfl_xor(p[i], d);
  const int w = tid >> 6, l = tid & 63;
  if (l == 0)
    for (int i = 0; i < 8; ++i) red[w * 8 + i] = p[i];
  __syncthreads();
  if (tid < 8) a2[r0 + tid] = red[tid] + red[8 + tid] + red[16 + tid] + red[24 + tid];
}

// ============================================================================
// K7: doc_vec = sum_s a2 * io2 ; out = doc @ W_final^T + b_final  (fp32 out)
// ============================================================================
__global__ __launch_bounds__(256) void k_final(
    const float* __restrict__ a2,
    const float* __restrict__ io2,
    const float* __restrict__ wf,    // [5][256] fp32
    const float* __restrict__ bfi,   // [5] fp32
    float* __restrict__ out)         // [64][5] fp32
{
  const int b = blockIdx.x, tid = threadIdx.x;
  __shared__ float av[S_];
  __shared__ float dv[256];
  __shared__ float red[4];
  if (tid < S_) av[tid] = a2[tid * 64 + b];
  __syncthreads();
  float acc = 0.f;
  for (int s = 0; s < S_; ++s) acc += av[s] * io2[((size_t)(s * 64 + b)) * 256 + tid];
  dv[tid] = acc;
  __syncthreads();
  for (int c = 0; c < C_; ++c) {
    float pv = wf[c * 256 + tid] * dv[tid];
    for (int d = 1; d < 64; d <<= 1) pv += __shfl_xor(pv, d);
    const int w = tid >> 6, l = tid & 63;
    if (l == 0) red[w] = pv;
    __syncthreads();
    if (tid == 0)
      out[b * C_ + c] = red[0] + red[1] + red[2] + red[3] + bfi[c];
    __syncthreads();
  }
}

// ============================================================================
extern "C" void kernel_launch(void* const* d_in, const int* in_sizes, int n_in,
                              void* d_out, int out_size, void* d_ws, size_t ws_size,
                              hipStream_t stream) {
  (void)in_sizes; (void)n_in; (void)out_size; (void)ws_size;
  const int*   tokens = (const int*)d_in[0];
  const float* emb    = (const float*)d_in[1];
  const float* wih_a  = (const float*)d_in[2];
  const float* whh_a  = (const float*)d_in[3];
  const float* bih_a  = (const float*)d_in[4];
  const float* bhh_a  = (const float*)d_in[5];
  const float* ww_a   = (const float*)d_in[6];
  const float* b_a    = (const float*)d_in[7];
  const float* proj_a = (const float*)d_in[8];
  const float* wih_i  = (const float*)d_in[9];
  const float* whh_i  = (const float*)d_in[10];
  const float* bih_i  = (const float*)d_in[11];
  const float* bhh_i  = (const float*)d_in[12];
  const float* ww_i   = (const float*)d_in[13];
  const float* b_i    = (const float*)d_in[14];
  const float* proj_i = (const float*)d_in[15];
  const float* w_fin  = (const float*)d_in[16];
  const float* b_fin  = (const float*)d_in[17];

  char* ws = (char*)d_ws;
  unsigned short* gtab = (unsigned short*)(ws + 0);          // 49,152,000 B
  unsigned short* wta  = (unsigned short*)(ws + 49152000);   //    131,072 B
  unsigned short* iout = (unsigned short*)(ws + 49283072);   // 67,108,864 B
  float* a1p = (float*)(ws + 116391936);                     //    524,288 B
  float* a1q = (float*)(ws + 116916224);                     //    524,288 B
  float* sv  = (float*)(ws + 117440512);                     //  2,097,152 B
  float* xgi = (float*)(ws + 119537664);                     //  6,291,456 B
  float* io2 = (float*)(ws + 125829120);                     //  2,097,152 B
  float* a2  = (float*)(ws + 127926272);                     //      8,192 B

  k_gtab<<<3004, 256, 0, stream>>>(emb, wih_a, bih_a, ww_a, gtab, wta);
  k_intra<<<512, 512, 0, stream>>>(tokens, gtab, whh_a, bhh_a, iout);
  k_attn1<<<512, 256, 0, stream>>>(iout, wta, b_a, proj_a, a1p, 0);
  k_attn1<<<512, 256, 0, stream>>>(iout, wta, b_a, proj_a, a1q, 1);
  k_attn2<<<2048, 256, 0, stream>>>(a1p, a1q, iout, sv);
  k_xgi<<<256, 256, 0, stream>>>(sv, wih_i, bih_i, xgi);
  k_inter<<<16, 512, 0, stream>>>(xgi, whh_i, bhh_i, io2);
  k_attn_i<<<256, 256, 0, stream>>>(io2, ww_i, b_i, proj_i, a2);
  k_final<<<64, 256, 0, stream>>>(a2, io2, w_fin, b_fin, (float*)d_out);
}

// Round 4
// 367.758 us; speedup vs baseline: 1.2474x; 1.2474x over previous
//
#include <hip/hip_runtime.h>

// Problem dims
#define S_ 32
#define T_ 64
#define B_ 64
#define V_ 32000
#define E_ 128
#define H_ 128
#define G_ 128
#define C_ 5

typedef short s8v __attribute__((ext_vector_type(8)));   // 8 bf16 payload
typedef __bf16 b8v __attribute__((ext_vector_type(8)));
typedef float f32x4 __attribute__((ext_vector_type(4)));

// --- MFMA wrapper: tolerate either builtin operand signature (short8 or bf16x8)
template <typename V>
__device__ inline auto mfma_sel(V a, V b, f32x4 c, int)
    -> decltype(__builtin_amdgcn_mfma_f32_16x16x32_bf16(a, b, c, 0, 0, 0)) {
  return __builtin_amdgcn_mfma_f32_16x16x32_bf16(a, b, c, 0, 0, 0);
}
template <typename V>
__device__ inline f32x4 mfma_sel(V a, V b, f32x4 c, long) {
  return __builtin_amdgcn_mfma_f32_16x16x32_bf16(
      __builtin_bit_cast(b8v, a), __builtin_bit_cast(b8v, b), c, 0, 0, 0);
}
__device__ inline f32x4 mfma16(s8v a, s8v b, f32x4 c) { return mfma_sel(a, b, c, 0); }

__device__ inline float b2f(unsigned short u) {
  union { unsigned int i; float f; } v; v.i = ((unsigned int)u) << 16; return v.f;
}
// round-to-nearest (ties away) — 2 instr; RNE tie diff is <=1ulp, irrelevant at 2% tol
__device__ inline unsigned short f2b(float f) {
  union { float f; unsigned int i; } v; v.f = f;
  return (unsigned short)((v.i + 0x8000u) >> 16);
}
// full-RNE for the precomputed tables (cheap there, done once per element)
__device__ inline unsigned short f2b_rne(float f) {
  union { float f; unsigned int i; } v; v.f = f;
  unsigned int r = (v.i + 0x7fffu + ((v.i >> 16) & 1u)) >> 16;
  return (unsigned short)r;
}
__device__ inline s8v cvt8(const float* p) {
  const float4 a = *(const float4*)p;
  const float4 b = *(const float4*)(p + 4);
  s8v r;
  r[0] = (short)f2b_rne(a.x); r[1] = (short)f2b_rne(a.y);
  r[2] = (short)f2b_rne(a.z); r[3] = (short)f2b_rne(a.w);
  r[4] = (short)f2b_rne(b.x); r[5] = (short)f2b_rne(b.y);
  r[6] = (short)f2b_rne(b.z); r[7] = (short)f2b_rne(b.w);
  return r;
}
// division-free activations: raw v_rcp_f32 + v_exp_f32 (1 instr each).
// Saturation: exp2(+inf)=inf -> rcp(inf)=0 -> exact asymptote; no clamps needed.
__device__ inline float fsigm(float x) {
  return __builtin_amdgcn_rcpf(1.f + __builtin_amdgcn_exp2f(-1.44269504f * x));
}
__device__ inline float ftanh(float x) {
  return 1.f - 2.f * __builtin_amdgcn_rcpf(1.f + __builtin_amdgcn_exp2f(2.88539008f * x));
}

// LDS-only barrier: waits LDS ops, does NOT drain vmcnt — global loads issued
// before this stay in flight across it (cross-wave data here is LDS-only).
__device__ inline void lds_barrier() {
  asm volatile("s_waitcnt lgkmcnt(0)\n\ts_barrier" ::: "memory");
}

// ============================================================================
// K1: gtab[v][c] = sum_e emb[v][e]*Wih_intra[c][e] + bih[c] (+bhh[c] folded for
// r,z gates). MFMA GEMM. Blocks 3000..3003: coalesced transpose of W_W_intra.
// ============================================================================
__global__ __launch_bounds__(256) void k_gtab(
    const float* __restrict__ emb,
    const float* __restrict__ wih,   // [768][128] fp32
    const float* __restrict__ bih,   // [768] fp32
    const float* __restrict__ bhh,   // [768] fp32 (r,z folded; n NOT)
    const float* __restrict__ wwi,   // [256][256] fp32 (h-major)
    unsigned short* __restrict__ gtab,   // [V][768] bf16
    unsigned short* __restrict__ wta)    // [256][256] bf16 (n-major)
{
  __shared__ __align__(16) unsigned short smem[64 * 264];  // union: alds / tbuf
  const int bid = blockIdx.x, tid = threadIdx.x;
  if (bid >= 3000) {  // LDS-tiled transpose, 4 blocks x 64 n-rows
    const int n0 = (bid - 3000) * 64;
    for (int i = 0; i < 64; ++i) {
      int cid = i * 256 + tid;
      int k = cid >> 6, nl = cid & 63;
      smem[nl * 264 + k] = f2b_rne(wwi[k * 256 + n0 + nl]);  // coalesced read
    }
    __syncthreads();
    for (int i = 0; i < 8; ++i) {
      int cid = i * 256 + tid;
      int nl = cid >> 5, k8 = cid & 31;
      *(int4*)&wta[(size_t)(n0 + nl) * 256 + k8 * 8] =
          *(const int4*)&smem[nl * 264 + k8 * 8];            // coalesced write
    }
    return;
  }
  const int mchunk = bid / 6, nchunk = bid % 6;
  const int vbase = mchunk * 64, nbase = nchunk * 128;
  for (int i = 0; i < 8; ++i) {
    int cid = i * 256 + tid;           // 2048 chunks of 4 floats
    int row = cid >> 5, kc = cid & 31;
    float4 v = *(const float4*)&emb[(size_t)(vbase + row) * 128 + kc * 4];
    ushort4 u;
    u.x = f2b_rne(v.x); u.y = f2b_rne(v.y); u.z = f2b_rne(v.z); u.w = f2b_rne(v.w);
    *(ushort4*)&smem[row * 136 + kc * 4] = u;
  }
  __syncthreads();
  const int w = tid >> 6, l = tid & 63, q = l >> 4, ln = l & 15;
  s8v bf[2][4];
  float bias[2];
  for (int nt = 0; nt < 2; ++nt) {
    int c = nbase + (w * 2 + nt) * 16 + ln;
    int g = (c < 384) ? c : (c - 384);       // gate index within direction
    bias[nt] = bih[c] + (g < 256 ? bhh[c] : 0.f);  // fold r,z recurrent bias
    for (int kf = 0; kf < 4; ++kf)
      bf[nt][kf] = cvt8(&wih[(size_t)c * 128 + kf * 32 + q * 8]);
  }
  for (int mt = 0; mt < 4; ++mt) {
    s8v af[4];
    for (int kf = 0; kf < 4; ++kf)
      af[kf] = *(const s8v*)&smem[(mt * 16 + ln) * 136 + kf * 32 + q * 8];
    for (int nt = 0; nt < 2; ++nt) {
      f32x4 acc = {0.f, 0.f, 0.f, 0.f};
      for (int kf = 0; kf < 4; ++kf) acc = mfma16(af[kf], bf[nt][kf], acc);
      const int col = nbase + (w * 2 + nt) * 16 + ln;
      for (int r = 0; r < 4; ++r) {
        const int row = vbase + mt * 16 + q * 4 + r;
        gtab[(size_t)row * 768 + col] = f2b_rne(acc[r] + bias[nt]);
      }
    }
  }
}

// ============================================================================
// K2: intra biGRU. Grid 256 = (s, dir, b-quad of 16): 16 REAL batches per
// N=16 tile (no duplicated lanes). Double-buffered h in LDS, one LDS-only
// barrier/step, next-step gate gather prefetched into registers.
// ============================================================================
__global__ __launch_bounds__(512) void k_intra(
    const int* __restrict__ tokens,
    const unsigned short* __restrict__ gtab,  // bf16, r/z biases folded
    const float* __restrict__ whh,            // [2][384][128] fp32
    const float* __restrict__ bhh,            // [2][384] fp32 (n-gate used)
    unsigned short* __restrict__ iout)        // [S*T*B][256] bf16 internal
{
  const int bid = blockIdx.x;
  const int s = bid >> 3, dir = (bid >> 2) & 1, bq = bid & 3;
  const int bbase = bq * 16;
  const int tid = threadIdx.x;
  const int w = tid >> 6, l = tid & 63, q = l >> 4, ln = l & 15;
  const int gbase = w * 16, g0 = gbase + q * 4;

  __shared__ __align__(16) unsigned short hb[2][16 * 136];
  __shared__ int tokl[T_ * 16];

  for (int i = tid; i < 2 * 16 * 136; i += 512) ((unsigned short*)hb)[i] = 0;
  for (int i = tid; i < T_ * 16; i += 512) {
    int t = i >> 4, bl = i & 15;
    tokl[i] = tokens[(s * T_ + t) * B_ + bbase + bl];
  }

  s8v af[3][4];
  float hbn[4];
  const float* whd = whh + (size_t)dir * (384 * 128);
  const float* bhd = bhh + dir * 384;
  for (int g3 = 0; g3 < 3; ++g3) {
    const int R = g3 * 128 + gbase;
    for (int kf = 0; kf < 4; ++kf)
      af[g3][kf] = cvt8(&whd[(size_t)(R + ln) * 128 + kf * 32 + q * 8]);
  }
  for (int r = 0; r < 4; ++r) hbn[r] = bhd[256 + gbase + q * 4 + r];  // n-gate only
  float h[4] = {0.f, 0.f, 0.f, 0.f};
  const int b = bbase + ln;
  __syncthreads();

  const int tfirst = dir ? (T_ - 1) : 0;
  const unsigned short* gr0 =
      gtab + (size_t)tokl[tfirst * 16 + ln] * 768 + dir * 384 + g0;
  ushort4 xr = *(const ushort4*)&gr0[0];
  ushort4 xz = *(const ushort4*)&gr0[128];
  ushort4 xn = *(const ushort4*)&gr0[256];

  int p = 0;
  for (int step = 0; step < T_; ++step) {
    const int t = dir ? (T_ - 1 - step) : step;
    const int t1 = dir ? (t > 0 ? t - 1 : 0) : (t < T_ - 1 ? t + 1 : T_ - 1);
    // prefetch next step's gates (stays in flight across the lds barrier)
    const unsigned short* grn =
        gtab + (size_t)tokl[t1 * 16 + ln] * 768 + dir * 384 + g0;
    const ushort4 xrn = *(const ushort4*)&grn[0];
    const ushort4 xzn = *(const ushort4*)&grn[128];
    const ushort4 xnn = *(const ushort4*)&grn[256];

    s8v bfr[4];
    for (int kf = 0; kf < 4; ++kf)
      bfr[kf] = *(const s8v*)&hb[p][ln * 136 + kf * 32 + q * 8];
    f32x4 c0 = {0.f, 0.f, 0.f, 0.f}, c1 = c0, c2 = c0;
    for (int kf = 0; kf < 4; ++kf) {
      c0 = mfma16(af[0][kf], bfr[kf], c0);
      c1 = mfma16(af[1][kf], bfr[kf], c1);
      c2 = mfma16(af[2][kf], bfr[kf], c2);
    }

    const unsigned short* xrp = (const unsigned short*)&xr;
    const unsigned short* xzp = (const unsigned short*)&xz;
    const unsigned short* xnp = (const unsigned short*)&xn;
    unsigned short hnb[4];
    for (int r = 0; r < 4; ++r) {
      float rr = fsigm(b2f(xrp[r]) + c0[r]);                 // bhh_r folded
      float zz = fsigm(b2f(xzp[r]) + c1[r]);                 // bhh_z folded
      float nn = ftanh(b2f(xnp[r]) + rr * (c2[r] + hbn[r])); // bhh_n inside r*()
      float hv = zz * (h[r] - nn) + nn;
      h[r] = hv;
      hnb[r] = f2b(hv);
    }
    ushort4 hv4; hv4.x = hnb[0]; hv4.y = hnb[1]; hv4.z = hnb[2]; hv4.w = hnb[3];
    *(ushort4*)&hb[p ^ 1][ln * 136 + g0] = hv4;
    *(ushort4*)&iout[((size_t)(s * T_ + t) * B_ + b) * 256 + dir * 128 + g0] = hv4;
    lds_barrier();
    p ^= 1;
    xr = xrn; xz = xzn; xn = xnn;
  }
}

// ============================================================================
// K3a: partial a1 logits = proj . tanh(iout @ W_W_intra + b), one N-half per
// launch, 256 rows/block (grid 512). Halves write independent arrays.
// ============================================================================
__global__ __launch_bounds__(256) void k_attn1(
    const unsigned short* __restrict__ iout,  // bf16 internal
    const unsigned short* __restrict__ wta,   // bf16 [256][256] n-major
    const float* __restrict__ bint,           // [256] fp32
    const float* __restrict__ proj,           // [256] fp32
    float* __restrict__ a1h, int half)
{
  __shared__ __align__(16) unsigned short wlds[128 * 256];  // 64 KB, XOR-swizzled
  const int tid = threadIdx.x, bid = blockIdx.x;
  const int nbg = half * 128;
  for (int i = 0; i < 16; ++i) {
    int cid = i * 256 + tid;          // 4096 16B chunks
    int n = cid >> 5, kc = cid & 31;
    *(int4*)&wlds[n * 256 + ((kc ^ (n & 15)) << 3)] =
        *(const int4*)&wta[(size_t)(nbg + n) * 256 + kc * 8];
  }
  __syncthreads();
  const int w = tid >> 6, l = tid & 63, q = l >> 4, ln = l & 15;
  const int rbase = bid * 256;
  for (int mt4 = 0; mt4 < 4; ++mt4) {
    const int mt = w * 4 + mt4;
    const int rowa = rbase + mt * 16 + ln;
    s8v af[8];
    for (int kf = 0; kf < 8; ++kf)
      af[kf] = *(const s8v*)&iout[(size_t)rowa * 256 + kf * 32 + q * 8];
    float p0 = 0.f, p1 = 0.f, p2 = 0.f, p3 = 0.f;
    for (int nt = 0; nt < 8; ++nt) {
      const int nloc = nt * 16 + ln;
      f32x4 c = {0.f, 0.f, 0.f, 0.f};
      for (int kf = 0; kf < 8; ++kf) {
        s8v bf = *(const s8v*)&wlds[nloc * 256 + (((kf * 4 + q) ^ (nloc & 15)) << 3)];
        c = mfma16(af[kf], bf, c);
      }
      const int ncol = nbg + nloc;
      const float bb = bint[ncol], pp = proj[ncol];
      p0 += pp * ftanh(c[0] + bb);
      p1 += pp * ftanh(c[1] + bb);
      p2 += pp * ftanh(c[2] + bb);
      p3 += pp * ftanh(c[3] + bb);
    }
    for (int d = 1; d < 16; d <<= 1) {
      p0 += __shfl_xor(p0, d);
      p1 += __shfl_xor(p1, d);
      p2 += __shfl_xor(p2, d);
      p3 += __shfl_xor(p3, d);
    }
    if (ln == 0) {
      const int row = rbase + mt * 16 + q * 4;
      a1h[row] = p0; a1h[row + 1] = p1; a1h[row + 2] = p2; a1h[row + 3] = p3;
    }
  }
}

// ============================================================================
// K3b: softmax over T per (s,b) + weighted sum -> sent_vecs fp32 [S*B][256]
// ============================================================================
__global__ __launch_bounds__(256) void k_attn2(
    const float* __restrict__ a1p, const float* __restrict__ a1q,
    const unsigned short* __restrict__ iout,
    float* __restrict__ sv)
{
  const int bid = blockIdx.x;
  const int s = bid >> 6, b = bid & 63;
  const int tid = threadIdx.x;
  __shared__ float wgt[T_];
  if (tid < 64) {
    const int idx = (s * T_ + tid) * B_ + b;
    float lg = a1p[idx] + a1q[idx];
    float m = lg;
    for (int d = 1; d < 64; d <<= 1) m = fmaxf(m, __shfl_xor(m, d));
    float e = __builtin_amdgcn_exp2f(1.44269504f * (lg - m));
    float sum = e;
    for (int d = 1; d < 64; d <<= 1) sum += __shfl_xor(sum, d);
    wgt[tid] = e * __builtin_amdgcn_rcpf(sum);
  }
  __syncthreads();
  float acc = 0.f;
  for (int t = 0; t < T_; ++t)
    acc += wgt[t] * b2f(iout[((size_t)(s * T_ + t) * B_ + b) * 256 + tid]);
  sv[(size_t)(s * B_ + b) * 256 + tid] = acc;
}

// ============================================================================
// K4: inter input gates xgi = sv @ Wih_inter^T + bih_inter (+bhh r,z folded)
// ============================================================================
__global__ __launch_bounds__(256) void k_xgi(
    const float* __restrict__ sv,
    const float* __restrict__ wihI,  // [768][256] fp32
    const float* __restrict__ bihI,  // [768] fp32
    const float* __restrict__ bhhI,  // [768] fp32
    float* __restrict__ xgi)         // [2][2048][384]
{
  const int bid = blockIdx.x, tid = threadIdx.x;
  const int r0 = bid * 8;
  __shared__ float svl[8 * 256];
  for (int i = 0; i < 8; ++i) svl[i * 256 + tid] = sv[(size_t)(r0 + i) * 256 + tid];
  __syncthreads();
  for (int cc = 0; cc < 3; ++cc) {
    const int c = cc * 256 + tid;
    const int dir = c / 384, g = c - dir * 384;
    const float bias = bihI[c] + (g < 256 ? bhhI[c] : 0.f);  // fold r,z
    float acc[8];
    for (int i = 0; i < 8; ++i) acc[i] = bias;
    const float* wr = wihI + (size_t)c * 256;
    for (int hh = 0; hh < 256; ++hh) {
      const float wv = wr[hh];
      for (int i = 0; i < 8; ++i) acc[i] += wv * svl[i * 256 + hh];
    }
    for (int i = 0; i < 8; ++i)
      xgi[((size_t)dir * 2048 + r0 + i) * 384 + g] = acc[i];
  }
}

// ============================================================================
// K5: inter biGRU. Grid 8 = (dir, b-quad of 16). Same pipeline as K2.
// ============================================================================
__global__ __launch_bounds__(512) void k_inter(
    const float* __restrict__ xgi,   // r,z biases folded
    const float* __restrict__ whh,   // [2][384][128] fp32
    const float* __restrict__ bhh,   // [2][384] fp32 (n-gate used)
    float* __restrict__ io2)         // [S*B][256] fp32
{
  const int bid = blockIdx.x;
  const int dir = bid >> 2, bq = bid & 3, bbase = bq * 16;
  const int tid = threadIdx.x;
  const int w = tid >> 6, l = tid & 63, q = l >> 4, ln = l & 15;
  const int gbase = w * 16, g0 = gbase + q * 4;
  __shared__ __align__(16) unsigned short hb[2][16 * 136];
  for (int i = tid; i < 2 * 16 * 136; i += 512) ((unsigned short*)hb)[i] = 0;
  s8v af[3][4];
  float hbn[4];
  const float* whd = whh + (size_t)dir * (384 * 128);
  const float* bhd = bhh + dir * 384;
  for (int g3 = 0; g3 < 3; ++g3) {
    const int R = g3 * 128 + gbase;
    for (int kf = 0; kf < 4; ++kf)
      af[g3][kf] = cvt8(&whd[(size_t)(R + ln) * 128 + kf * 32 + q * 8]);
  }
  for (int r = 0; r < 4; ++r) hbn[r] = bhd[256 + gbase + q * 4 + r];
  float h[4] = {0.f, 0.f, 0.f, 0.f};
  const int b = bbase + ln;
  __syncthreads();

  const int sfirst = dir ? (S_ - 1) : 0;
  const float* xp0 = xgi + ((size_t)dir * 2048 + sfirst * 64 + b) * 384 + g0;
  float4 vr = *(const float4*)&xp0[0];
  float4 vz = *(const float4*)&xp0[128];
  float4 vn = *(const float4*)&xp0[256];

  int p = 0;
  for (int step = 0; step < S_; ++step) {
    const int sI = dir ? (S_ - 1 - step) : step;
    const int s1 = dir ? (sI > 0 ? sI - 1 : 0) : (sI < S_ - 1 ? sI + 1 : S_ - 1);
    const float* xpn = xgi + ((size_t)dir * 2048 + s1 * 64 + b) * 384 + g0;
    const float4 vrn = *(const float4*)&xpn[0];
    const float4 vzn = *(const float4*)&xpn[128];
    const float4 vnn = *(const float4*)&xpn[256];

    s8v bfr[4];
    for (int kf = 0; kf < 4; ++kf)
      bfr[kf] = *(const s8v*)&hb[p][ln * 136 + kf * 32 + q * 8];
    f32x4 c0 = {0.f, 0.f, 0.f, 0.f}, c1 = c0, c2 = c0;
    for (int kf = 0; kf < 4; ++kf) {
      c0 = mfma16(af[0][kf], bfr[kf], c0);
      c1 = mfma16(af[1][kf], bfr[kf], c1);
      c2 = mfma16(af[2][kf], bfr[kf], c2);
    }
    const float irv[4] = {vr.x, vr.y, vr.z, vr.w};
    const float izv[4] = {vz.x, vz.y, vz.z, vz.w};
    const float inv[4] = {vn.x, vn.y, vn.z, vn.w};
    unsigned short hnb[4];
    for (int r = 0; r < 4; ++r) {
      float rr = fsigm(irv[r] + c0[r]);
      float zz = fsigm(izv[r] + c1[r]);
      float nn = ftanh(inv[r] + rr * (c2[r] + hbn[r]));
      float hv = zz * (h[r] - nn) + nn;
      h[r] = hv;
      hnb[r] = f2b(hv);
    }
    ushort4 hv4; hv4.x = hnb[0]; hv4.y = hnb[1]; hv4.z = hnb[2]; hv4.w = hnb[3];
    *(ushort4*)&hb[p ^ 1][ln * 136 + g0] = hv4;
    float4 of4; of4.x = h[0]; of4.y = h[1]; of4.z = h[2]; of4.w = h[3];
    *(float4*)&io2[((size_t)(sI * 64 + b)) * 256 + dir * 128 + g0] = of4;
    lds_barrier();
    p ^= 1;
    vr = vrn; vz = vzn; vn = vnn;
  }
}

// ============================================================================
// K6: a2[s*64+b] = proj_inter . tanh(io2 @ W_W_inter + b_inter)  (no softmax)
// ============================================================================
__global__ __launch_bounds__(256) void k_attn_i(
    const float* __restrict__ io2,
    const float* __restrict__ wwI,   // [256][256] fp32 h-major
    const float* __restrict__ bI,
    const float* __restrict__ projI,
    float* __restrict__ a2)          // [2048]
{
  const int bid = blockIdx.x, tid = threadIdx.x;
  const int r0 = bid * 8;
  __shared__ float iol[8 * 256];
  __shared__ float red[4 * 8];
  for (int i = 0; i < 8; ++i) iol[i * 256 + tid] = io2[(size_t)(r0 + i) * 256 + tid];
  __syncthreads();
  float acc[8];
  for (int i = 0; i < 8; ++i) acc[i] = 0.f;
  for (int hh = 0; hh < 256; ++hh) {
    const float wv = wwI[hh * 256 + tid];
    for (int i = 0; i < 8; ++i) acc[i] += wv * iol[i * 256 + hh];
  }
  const float bb = bI[tid], pp = projI[tid];
  float p[8];
  for (int i = 0; i < 8; ++i) p[i] = pp * ftanh(acc[i] + bb);
  for (int d = 1; d < 64; d <<= 1)
    for (int i = 0; i < 8; ++i) p[i] += __shfl_xor(p[i], d);
  const int w = tid >> 6, l = tid & 63;
  if (l == 0)
    for (int i = 0; i < 8; ++i) red[w * 8 + i] = p[i];
  __syncthreads();
  if (tid < 8) a2[r0 + tid] = red[tid] + red[8 + tid] + red[16 + tid] + red[24 + tid];
}

// ============================================================================
// K7: doc_vec = sum_s a2 * io2 ; out = doc @ W_final^T + b_final  (fp32 out)
// ============================================================================
__global__ __launch_bounds__(256) void k_final(
    const float* __restrict__ a2,
    const float* __restrict__ io2,
    const float* __restrict__ wf,    // [5][256] fp32
    const float* __restrict__ bfi,   // [5] fp32
    float* __restrict__ out)         // [64][5] fp32
{
  const int b = blockIdx.x, tid = threadIdx.x;
  __shared__ float av[S_];
  __shared__ float dv[256];
  __shared__ float red[4];
  if (tid < S_) av[tid] = a2[tid * 64 + b];
  __syncthreads();
  float acc = 0.f;
  for (int s = 0; s < S_; ++s) acc += av[s] * io2[((size_t)(s * 64 + b)) * 256 + tid];
  dv[tid] = acc;
  __syncthreads();
  for (int c = 0; c < C_; ++c) {
    float pv = wf[c * 256 + tid] * dv[tid];
    for (int d = 1; d < 64; d <<= 1) pv += __shfl_xor(pv, d);
    const int w = tid >> 6, l = tid & 63;
    if (l == 0) red[w] = pv;
    __syncthreads();
    if (tid == 0)
      out[b * C_ + c] = red[0] + red[1] + red[2] + red[3] + bfi[c];
    __syncthreads();
  }
}

// ============================================================================
extern "C" void kernel_launch(void* const* d_in, const int* in_sizes, int n_in,
                              void* d_out, int out_size, void* d_ws, size_t ws_size,
                              hipStream_t stream) {
  (void)in_sizes; (void)n_in; (void)out_size; (void)ws_size;
  const int*   tokens = (const int*)d_in[0];
  const float* emb    = (const float*)d_in[1];
  const float* wih_a  = (const float*)d_in[2];
  const float* whh_a  = (const float*)d_in[3];
  const float* bih_a  = (const float*)d_in[4];
  const float* bhh_a  = (const float*)d_in[5];
  const float* ww_a   = (const float*)d_in[6];
  const float* b_a    = (const float*)d_in[7];
  const float* proj_a = (const float*)d_in[8];
  const float* wih_i  = (const float*)d_in[9];
  const float* whh_i  = (const float*)d_in[10];
  const float* bih_i  = (const float*)d_in[11];
  const float* bhh_i  = (const float*)d_in[12];
  const float* ww_i   = (const float*)d_in[13];
  const float* b_i    = (const float*)d_in[14];
  const float* proj_i = (const float*)d_in[15];
  const float* w_fin  = (const float*)d_in[16];
  const float* b_fin  = (const float*)d_in[17];

  char* ws = (char*)d_ws;
  unsigned short* gtab = (unsigned short*)(ws + 0);          // 49,152,000 B
  unsigned short* wta  = (unsigned short*)(ws + 49152000);   //    131,072 B
  unsigned short* iout = (unsigned short*)(ws + 49283072);   // 67,108,864 B
  float* a1p = (float*)(ws + 116391936);                     //    524,288 B
  float* a1q = (float*)(ws + 116916224);                     //    524,288 B
  float* sv  = (float*)(ws + 117440512);                     //  2,097,152 B
  float* xgi = (float*)(ws + 119537664);                     //  6,291,456 B
  float* io2 = (float*)(ws + 125829120);                     //  2,097,152 B
  float* a2  = (float*)(ws + 127926272);                     //      8,192 B

  k_gtab<<<3004, 256, 0, stream>>>(emb, wih_a, bih_a, bhh_a, ww_a, gtab, wta);
  k_intra<<<256, 512, 0, stream>>>(tokens, gtab, whh_a, bhh_a, iout);
  k_attn1<<<512, 256, 0, stream>>>(iout, wta, b_a, proj_a, a1p, 0);
  k_attn1<<<512, 256, 0, stream>>>(iout, wta, b_a, proj_a, a1q, 1);
  k_attn2<<<2048, 256, 0, stream>>>(a1p, a1q, iout, sv);
  k_xgi<<<256, 256, 0, stream>>>(sv, wih_i, bih_i, bhh_i, xgi);
  k_inter<<<8, 512, 0, stream>>>(xgi, whh_i, bhh_i, io2);
  k_attn_i<<<256, 256, 0, stream>>>(io2, ww_i, b_i, proj_i, a2);
  k_final<<<64, 256, 0, stream>>>(a2, io2, w_fin, b_fin, (float*)d_out);
}